// Round 2
// baseline (461.215 us; speedup 1.0000x reference)
//
#include <hip/hip_runtime.h>

#define NN 100000
#define HC 128
#define NE 1600000

// ---------------------------------------------------------------------------
// Stage 1: per-node linear precompute.
//   UV[n][o]       = U[n][o] = sum_h z[n][h] * W1[o][h]        (o in [0,128))
//   UV[n][128+o]   = V[n][o] = sum_h z[n][h] * W1[o][128+h]
// One thread = one node x one 32-output group (blockIdx.y selects group).
// W1 offsets are wave-uniform -> scalar loads; z streamed as float4.
// ---------------------------------------------------------------------------
__global__ __launch_bounds__(256) void precompute_uv_kernel(
    const float* __restrict__ z, const float* __restrict__ W1,
    float* __restrict__ UV) {
  const int node = blockIdx.x * 256 + threadIdx.x;
  if (node >= NN) return;
  const int og = blockIdx.y * 32;  // 0,32,...,224
  const float* __restrict__ zr = z + (size_t)node * HC;

  float acc[32];
#pragma unroll
  for (int j = 0; j < 32; ++j) acc[j] = 0.f;

#pragma unroll 1
  for (int hc = 0; hc < HC; hc += 16) {
    float zz[16];
#pragma unroll
    for (int i = 0; i < 4; ++i) {
      const float4 t = *(const float4*)(zr + hc + 4 * i);
      zz[4 * i + 0] = t.x; zz[4 * i + 1] = t.y;
      zz[4 * i + 2] = t.z; zz[4 * i + 3] = t.w;
    }
#pragma unroll
    for (int j = 0; j < 32; ++j) {
      const int o = og + j;
      // U part (o<128): W1[o][h];  V part (o>=128): W1[o-128][128+h]
      const float* __restrict__ wrow =
          W1 + ((size_t)(o & 127) << 8) + ((o >> 7) << 7) + hc;
#pragma unroll
      for (int h = 0; h < 16; ++h) acc[j] = fmaf(zz[h], wrow[h], acc[j]);
    }
  }

  float* __restrict__ op = UV + (size_t)node * 256 + og;
#pragma unroll
  for (int j = 0; j < 32; j += 4)
    *(float4*)(op + j) = make_float4(acc[j], acc[j + 1], acc[j + 2], acc[j + 3]);
}

// ---------------------------------------------------------------------------
// Stage 2: per-edge decode. 16 lanes per edge; lane l owns elements
// [4l..4l+3] and [64+4l..64+4l+3] of the 128-dim hidden vector.
//   out[e] = sum_o w2[o] * lrelu(U[row][o] + V[col][o] + b1[o]) + b2
// ---------------------------------------------------------------------------
__global__ __launch_bounds__(256) void edge_decode_kernel(
    const int* __restrict__ eidx, const float* __restrict__ UV,
    const float* __restrict__ b1, const float* __restrict__ W2,
    const float* __restrict__ b2, float* __restrict__ out) {
  const int lane = threadIdx.x & 15;
  const int qw = (blockIdx.x * 256 + threadIdx.x) >> 4;
  const int nqw = (gridDim.x * 256) >> 4;

  // loop-invariant fragments, kept in registers
  const float4 b1a = ((const float4*)b1)[lane];
  const float4 b1b = ((const float4*)b1)[16 + lane];
  const float4 w2a = ((const float4*)W2)[lane];
  const float4 w2b = ((const float4*)W2)[16 + lane];
  const float bias2 = b2[0];

  const int* __restrict__ rows = eidx;
  const int* __restrict__ cols = eidx + NE;

#pragma unroll 2
  for (int e = qw; e < NE; e += nqw) {
    const int r = rows[e];
    const int c = cols[e];
    const float4* __restrict__ up = (const float4*)(UV + (size_t)r * 256);
    const float4* __restrict__ vp = (const float4*)(UV + (size_t)c * 256 + 128);
    const float4 u0 = up[lane];
    const float4 u1 = up[16 + lane];
    const float4 v0 = vp[lane];
    const float4 v1 = vp[16 + lane];

    float s = 0.f;
    float t;
#define STEP(U_, V_, B_, W_)                                   \
    t = U_ + V_ + B_; t = (t >= 0.f) ? t : 0.01f * t;          \
    s = fmaf(t, W_, s);
    STEP(u0.x, v0.x, b1a.x, w2a.x)
    STEP(u0.y, v0.y, b1a.y, w2a.y)
    STEP(u0.z, v0.z, b1a.z, w2a.z)
    STEP(u0.w, v0.w, b1a.w, w2a.w)
    STEP(u1.x, v1.x, b1b.x, w2b.x)
    STEP(u1.y, v1.y, b1b.y, w2b.y)
    STEP(u1.z, v1.z, b1b.z, w2b.z)
    STEP(u1.w, v1.w, b1b.w, w2b.w)
#undef STEP

    // reduce across the 16-lane group (xor masks <= 8 stay in-group)
    s += __shfl_xor(s, 8);
    s += __shfl_xor(s, 4);
    s += __shfl_xor(s, 2);
    s += __shfl_xor(s, 1);
    if (lane == 0) out[e] = s + bias2;
  }
}

// ---------------------------------------------------------------------------
// Fallback (only if workspace is too small): direct per-edge compute.
// One wave per edge; lane computes outputs o=lane and o=lane+64.
// Slow but correct; not expected to run.
// ---------------------------------------------------------------------------
__global__ __launch_bounds__(64) void edge_direct_kernel(
    const float* __restrict__ z, const int* __restrict__ eidx,
    const float* __restrict__ W1, const float* __restrict__ b1,
    const float* __restrict__ W2, const float* __restrict__ b2,
    float* __restrict__ out) {
  const int lane = threadIdx.x;
  const int o0 = lane, o1 = lane + 64;
  const float w2_0 = W2[o0], w2_1 = W2[o1];
  const float b1_0 = b1[o0], b1_1 = b1[o1];
  const float bias2 = b2[0];

  for (int e = blockIdx.x; e < NE; e += gridDim.x) {
    const int r = eidx[e];
    const int c = eidx[e + NE];
    const float* __restrict__ zr = z + (size_t)r * HC;
    const float* __restrict__ zc = z + (size_t)c * HC;
    float a0 = 0.f, a1 = 0.f;
    for (int h = 0; h < HC; ++h) {
      const float zrh = zr[h], zch = zc[h];
      a0 = fmaf(zrh, W1[(size_t)o0 * 256 + h], a0);
      a0 = fmaf(zch, W1[(size_t)o0 * 256 + 128 + h], a0);
      a1 = fmaf(zrh, W1[(size_t)o1 * 256 + h], a1);
      a1 = fmaf(zch, W1[(size_t)o1 * 256 + 128 + h], a1);
    }
    a0 += b1_0; a1 += b1_1;
    a0 = (a0 >= 0.f) ? a0 : 0.01f * a0;
    a1 = (a1 >= 0.f) ? a1 : 0.01f * a1;
    float s = fmaf(a0, w2_0, a1 * w2_1);
    for (int off = 32; off >= 1; off >>= 1) s += __shfl_xor(s, off);
    if (lane == 0) out[e] = s + bias2;
  }
}

extern "C" void kernel_launch(void* const* d_in, const int* in_sizes, int n_in,
                              void* d_out, int out_size, void* d_ws, size_t ws_size,
                              hipStream_t stream) {
  const float* z  = (const float*)d_in[0];
  const int*   ei = (const int*)d_in[1];
  const float* W1 = (const float*)d_in[2];
  const float* b1 = (const float*)d_in[3];
  const float* W2 = (const float*)d_in[4];
  const float* b2 = (const float*)d_in[5];
  float* out = (float*)d_out;

  const size_t need = (size_t)NN * 256 * sizeof(float);  // 102.4 MB
  if (ws_size >= need) {
    float* UV = (float*)d_ws;
    dim3 g1((NN + 255) / 256, 8);
    precompute_uv_kernel<<<g1, 256, 0, stream>>>(z, W1, UV);
    edge_decode_kernel<<<2048, 256, 0, stream>>>(ei, UV, b1, W2, b2, out);
  } else {
    edge_direct_kernel<<<8192, 64, 0, stream>>>(z, ei, W1, b1, W2, b2, out);
  }
}

// Round 3
// 321.900 us; speedup vs baseline: 1.4328x; 1.4328x over previous
//
#include <hip/hip_runtime.h>

#define NN 100000
#define HC 128
#define NE 1600000
#define PADK 132  // padded LDS row stride (floats); 132%32=4 -> benign 2-way/broadcast banks

// ---------------------------------------------------------------------------
// Prep: Wt[k][o] (128 x 256) from W1 (128 x 256 row-major, [o][h]):
//   o <  128 : Wt[k][o] = W1[o][k]        (U weights)
//   o >= 128 : Wt[k][o] = W1[o-128][128+k] (V weights)
// Coalesced read of W1, scattered write (only 128 KB total).
// ---------------------------------------------------------------------------
__global__ __launch_bounds__(256) void transpose_w1_kernel(
    const float* __restrict__ W1, float* __restrict__ Wt) {
  const int idx = blockIdx.x * 256 + threadIdx.x;  // over 128*256
  if (idx >= 128 * 256) return;
  const int row = idx >> 8;    // source row o_r in [0,128)
  const int c = idx & 255;     // source col
  const int k = c & 127;
  const int o = (c >> 7) ? (row + 128) : row;
  Wt[k * 256 + o] = W1[idx];
}

// ---------------------------------------------------------------------------
// Stage 1 v2: UV[n][o] = sum_k z[n][k] * Wt[k][o], tiled.
// Block: 64 nodes, 256 threads. z tile staged once in LDS.
// Thread (to = t&31, tn = t>>5): 8 nodes (tn*8..+7) x 8 outputs (to*8..+7),
// acc[8][8] in registers. Per k: Wt row read coalesced (2 x float4/lane),
// z from LDS as 32-lane broadcasts (conflict-free).
// ---------------------------------------------------------------------------
__global__ __launch_bounds__(256) void precompute_uv_v2_kernel(
    const float* __restrict__ z, const float* __restrict__ Wt,
    float* __restrict__ UV) {
  __shared__ float zs[64 * PADK];

  const int t = threadIdx.x;
  const int nb = blockIdx.x * 64;

  // ---- stage z tile: 64 rows x 128 floats = 2048 float4, 8 per thread ----
#pragma unroll
  for (int i = 0; i < 8; ++i) {
    const int f = t + 256 * i;        // float4 index in tile
    const int row = f >> 5;           // node within tile
    const int q = f & 31;             // float4 within row
    const int node = nb + row;
    float4 v = make_float4(0.f, 0.f, 0.f, 0.f);
    if (node < NN) v = *(const float4*)(z + (size_t)node * HC + q * 4);
    *(float4*)&zs[row * PADK + q * 4] = v;
  }
  __syncthreads();

  const int to = t & 31;   // output octet: o = to*8 + j
  const int tn = t >> 5;   // node octet:   n = tn*8 + i

  float acc[8][8];
#pragma unroll
  for (int i = 0; i < 8; ++i)
#pragma unroll
    for (int j = 0; j < 8; ++j) acc[i][j] = 0.f;

  const float4* __restrict__ wp = (const float4*)Wt;  // [k*64 + o4]
  const float* __restrict__ zrow = &zs[tn * 8 * PADK];

#pragma unroll 1
  for (int k = 0; k < HC; k += 4) {
    float4 zq[8];
#pragma unroll
    for (int i = 0; i < 8; ++i)
      zq[i] = *(const float4*)(zrow + i * PADK + k);

#pragma unroll
    for (int kk = 0; kk < 4; ++kk) {
      const float4 w0 = wp[(k + kk) * 64 + to * 2];
      const float4 w1 = wp[(k + kk) * 64 + to * 2 + 1];
      const float wj[8] = {w0.x, w0.y, w0.z, w0.w, w1.x, w1.y, w1.z, w1.w};
#pragma unroll
      for (int i = 0; i < 8; ++i) {
        const float zv = (kk == 0) ? zq[i].x
                       : (kk == 1) ? zq[i].y
                       : (kk == 2) ? zq[i].z : zq[i].w;
#pragma unroll
        for (int j = 0; j < 8; ++j)
          acc[i][j] = fmaf(zv, wj[j], acc[i][j]);
      }
    }
  }

  // ---- store: UV[n][to*8 .. to*8+7] ----
#pragma unroll
  for (int i = 0; i < 8; ++i) {
    const int node = nb + tn * 8 + i;
    if (node < NN) {
      float* op = UV + (size_t)node * 256 + to * 8;
      *(float4*)op = make_float4(acc[i][0], acc[i][1], acc[i][2], acc[i][3]);
      *(float4*)(op + 4) = make_float4(acc[i][4], acc[i][5], acc[i][6], acc[i][7]);
    }
  }
}

// ---------------------------------------------------------------------------
// Stage 2: per-edge decode (unchanged from round 2; ~L3-gather-bound).
// ---------------------------------------------------------------------------
__global__ __launch_bounds__(256) void edge_decode_kernel(
    const int* __restrict__ eidx, const float* __restrict__ UV,
    const float* __restrict__ b1, const float* __restrict__ W2,
    const float* __restrict__ b2, float* __restrict__ out) {
  const int lane = threadIdx.x & 15;
  const int qw = (blockIdx.x * 256 + threadIdx.x) >> 4;
  const int nqw = (gridDim.x * 256) >> 4;

  const float4 b1a = ((const float4*)b1)[lane];
  const float4 b1b = ((const float4*)b1)[16 + lane];
  const float4 w2a = ((const float4*)W2)[lane];
  const float4 w2b = ((const float4*)W2)[16 + lane];
  const float bias2 = b2[0];

  const int* __restrict__ rows = eidx;
  const int* __restrict__ cols = eidx + NE;

#pragma unroll 2
  for (int e = qw; e < NE; e += nqw) {
    const int r = rows[e];
    const int c = cols[e];
    const float4* __restrict__ up = (const float4*)(UV + (size_t)r * 256);
    const float4* __restrict__ vp = (const float4*)(UV + (size_t)c * 256 + 128);
    const float4 u0 = up[lane];
    const float4 u1 = up[16 + lane];
    const float4 v0 = vp[lane];
    const float4 v1 = vp[16 + lane];

    float s = 0.f;
    float t;
#define STEP(U_, V_, B_, W_)                                   \
    t = U_ + V_ + B_; t = (t >= 0.f) ? t : 0.01f * t;          \
    s = fmaf(t, W_, s);
    STEP(u0.x, v0.x, b1a.x, w2a.x)
    STEP(u0.y, v0.y, b1a.y, w2a.y)
    STEP(u0.z, v0.z, b1a.z, w2a.z)
    STEP(u0.w, v0.w, b1a.w, w2a.w)
    STEP(u1.x, v1.x, b1b.x, w2b.x)
    STEP(u1.y, v1.y, b1b.y, w2b.y)
    STEP(u1.z, v1.z, b1b.z, w2b.z)
    STEP(u1.w, v1.w, b1b.w, w2b.w)
#undef STEP

    s += __shfl_xor(s, 8);
    s += __shfl_xor(s, 4);
    s += __shfl_xor(s, 2);
    s += __shfl_xor(s, 1);
    if (lane == 0) out[e] = s + bias2;
  }
}

// ---------------------------------------------------------------------------
// Fallbacks if workspace is too small (correct, slower).
// ---------------------------------------------------------------------------
__global__ __launch_bounds__(256) void precompute_uv_kernel(
    const float* __restrict__ z, const float* __restrict__ W1,
    float* __restrict__ UV) {
  const int node = blockIdx.x * 256 + threadIdx.x;
  if (node >= NN) return;
  const int og = blockIdx.y * 32;
  const float* __restrict__ zr = z + (size_t)node * HC;

  float acc[32];
#pragma unroll
  for (int j = 0; j < 32; ++j) acc[j] = 0.f;

#pragma unroll 1
  for (int hc = 0; hc < HC; hc += 16) {
    float zz[16];
#pragma unroll
    for (int i = 0; i < 4; ++i) {
      const float4 tv = *(const float4*)(zr + hc + 4 * i);
      zz[4 * i + 0] = tv.x; zz[4 * i + 1] = tv.y;
      zz[4 * i + 2] = tv.z; zz[4 * i + 3] = tv.w;
    }
#pragma unroll
    for (int j = 0; j < 32; ++j) {
      const int o = og + j;
      const float* __restrict__ wrow =
          W1 + ((size_t)(o & 127) << 8) + ((o >> 7) << 7) + hc;
#pragma unroll
      for (int h = 0; h < 16; ++h) acc[j] = fmaf(zz[h], wrow[h], acc[j]);
    }
  }

  float* __restrict__ op = UV + (size_t)node * 256 + og;
#pragma unroll
  for (int j = 0; j < 32; j += 4)
    *(float4*)(op + j) = make_float4(acc[j], acc[j + 1], acc[j + 2], acc[j + 3]);
}

__global__ __launch_bounds__(64) void edge_direct_kernel(
    const float* __restrict__ z, const int* __restrict__ eidx,
    const float* __restrict__ W1, const float* __restrict__ b1,
    const float* __restrict__ W2, const float* __restrict__ b2,
    float* __restrict__ out) {
  const int lane = threadIdx.x;
  const int o0 = lane, o1 = lane + 64;
  const float w2_0 = W2[o0], w2_1 = W2[o1];
  const float b1_0 = b1[o0], b1_1 = b1[o1];
  const float bias2 = b2[0];

  for (int e = blockIdx.x; e < NE; e += gridDim.x) {
    const int r = eidx[e];
    const int c = eidx[e + NE];
    const float* __restrict__ zr = z + (size_t)r * HC;
    const float* __restrict__ zc = z + (size_t)c * HC;
    float a0 = 0.f, a1 = 0.f;
    for (int h = 0; h < HC; ++h) {
      const float zrh = zr[h], zch = zc[h];
      a0 = fmaf(zrh, W1[(size_t)o0 * 256 + h], a0);
      a0 = fmaf(zch, W1[(size_t)o0 * 256 + 128 + h], a0);
      a1 = fmaf(zrh, W1[(size_t)o1 * 256 + h], a1);
      a1 = fmaf(zch, W1[(size_t)o1 * 256 + 128 + h], a1);
    }
    a0 += b1_0; a1 += b1_1;
    a0 = (a0 >= 0.f) ? a0 : 0.01f * a0;
    a1 = (a1 >= 0.f) ? a1 : 0.01f * a1;
    float s = fmaf(a0, w2_0, a1 * w2_1);
    for (int off = 32; off >= 1; off >>= 1) s += __shfl_xor(s, off);
    if (lane == 0) out[e] = s + bias2;
  }
}

extern "C" void kernel_launch(void* const* d_in, const int* in_sizes, int n_in,
                              void* d_out, int out_size, void* d_ws, size_t ws_size,
                              hipStream_t stream) {
  const float* z  = (const float*)d_in[0];
  const int*   ei = (const int*)d_in[1];
  const float* W1 = (const float*)d_in[2];
  const float* b1 = (const float*)d_in[3];
  const float* W2 = (const float*)d_in[4];
  const float* b2 = (const float*)d_in[5];
  float* out = (float*)d_out;

  const size_t uv_bytes = (size_t)NN * 256 * sizeof(float);      // 102,400,000
  const size_t wt_bytes = (size_t)128 * 256 * sizeof(float);     // 131,072

  if (ws_size >= uv_bytes + wt_bytes) {
    float* UV = (float*)d_ws;
    float* Wt = (float*)((char*)d_ws + uv_bytes);
    transpose_w1_kernel<<<128, 256, 0, stream>>>(W1, Wt);
    precompute_uv_v2_kernel<<<(NN + 63) / 64, 256, 0, stream>>>(z, Wt, UV);
    edge_decode_kernel<<<2048, 256, 0, stream>>>(ei, UV, b1, W2, b2, out);
  } else if (ws_size >= uv_bytes) {
    float* UV = (float*)d_ws;
    dim3 g1((NN + 255) / 256, 8);
    precompute_uv_kernel<<<g1, 256, 0, stream>>>(z, W1, UV);
    edge_decode_kernel<<<2048, 256, 0, stream>>>(ei, UV, b1, W2, b2, out);
  } else {
    edge_direct_kernel<<<8192, 64, 0, stream>>>(z, ei, W1, b1, W2, b2, out);
  }
}

// Round 4
// 201.147 us; speedup vs baseline: 2.2929x; 1.6003x over previous
//
#include <hip/hip_runtime.h>
#include <hip/hip_fp16.h>

#define NN 100000
#define HC 128
#define NE 1600000
#define PADK 132  // padded LDS row stride (floats)

// ---------------------------------------------------------------------------
// Prep: Wt[k][o] (128 x 256) from W1 (128 x 256 row-major, [o][h]):
//   o <  128 : Wt[k][o] = W1[o][k]         (U weights)
//   o >= 128 : Wt[k][o] = W1[o-128][128+k] (V weights)
// ---------------------------------------------------------------------------
__global__ __launch_bounds__(256) void transpose_w1_kernel(
    const float* __restrict__ W1, float* __restrict__ Wt) {
  const int idx = blockIdx.x * 256 + threadIdx.x;  // over 128*256
  if (idx >= 128 * 256) return;
  const int row = idx >> 8;    // source row o_r in [0,128)
  const int c = idx & 255;     // source col
  const int k = c & 127;
  const int o = (c >> 7) ? (row + 128) : row;
  Wt[k * 256 + o] = W1[idx];
}

// ---------------------------------------------------------------------------
// Stage 1: UV[n][o] = sum_k z[n][k] * Wt[k][o], tiled GEMM, fp32 compute,
// fp16 store. Block: 64 nodes, 256 threads, z tile staged once in LDS.
// Thread (to = t&31, tn = t>>5): 8 nodes x 8 outputs, acc[8][8] in regs.
// ---------------------------------------------------------------------------
__global__ __launch_bounds__(256) void precompute_uv_f16_kernel(
    const float* __restrict__ z, const float* __restrict__ Wt,
    __half* __restrict__ UV) {
  __shared__ float zs[64 * PADK];

  const int t = threadIdx.x;
  const int nb = blockIdx.x * 64;

  // ---- stage z tile: 64 rows x 128 floats = 2048 float4, 8 per thread ----
#pragma unroll
  for (int i = 0; i < 8; ++i) {
    const int f = t + 256 * i;        // float4 index in tile
    const int row = f >> 5;           // node within tile
    const int q = f & 31;             // float4 within row
    const int node = nb + row;
    float4 v = make_float4(0.f, 0.f, 0.f, 0.f);
    if (node < NN) v = *(const float4*)(z + (size_t)node * HC + q * 4);
    *(float4*)&zs[row * PADK + q * 4] = v;
  }
  __syncthreads();

  const int to = t & 31;   // output octet: o = to*8 + j
  const int tn = t >> 5;   // node octet:   n = tn*8 + i

  float acc[8][8];
#pragma unroll
  for (int i = 0; i < 8; ++i)
#pragma unroll
    for (int j = 0; j < 8; ++j) acc[i][j] = 0.f;

  const float4* __restrict__ wp = (const float4*)Wt;  // [k*64 + o4]
  const float* __restrict__ zrow = &zs[tn * 8 * PADK];

#pragma unroll 1
  for (int k = 0; k < HC; k += 4) {
    float4 zq[8];
#pragma unroll
    for (int i = 0; i < 8; ++i)
      zq[i] = *(const float4*)(zrow + i * PADK + k);

#pragma unroll
    for (int kk = 0; kk < 4; ++kk) {
      const float4 w0 = wp[(k + kk) * 64 + to * 2];
      const float4 w1 = wp[(k + kk) * 64 + to * 2 + 1];
      const float wj[8] = {w0.x, w0.y, w0.z, w0.w, w1.x, w1.y, w1.z, w1.w};
#pragma unroll
      for (int i = 0; i < 8; ++i) {
        const float zv = (kk == 0) ? zq[i].x
                       : (kk == 1) ? zq[i].y
                       : (kk == 2) ? zq[i].z : zq[i].w;
#pragma unroll
        for (int j = 0; j < 8; ++j)
          acc[i][j] = fmaf(zv, wj[j], acc[i][j]);
      }
    }
  }

  // ---- store as fp16: UV[n][to*8 .. to*8+7], one uint4 per node ----
#pragma unroll
  for (int i = 0; i < 8; ++i) {
    const int node = nb + tn * 8 + i;
    if (node < NN) {
      union { uint4 u; __half2 h[4]; } pk;
      pk.h[0] = __floats2half2_rn(acc[i][0], acc[i][1]);
      pk.h[1] = __floats2half2_rn(acc[i][2], acc[i][3]);
      pk.h[2] = __floats2half2_rn(acc[i][4], acc[i][5]);
      pk.h[3] = __floats2half2_rn(acc[i][6], acc[i][7]);
      *(uint4*)(UV + (size_t)node * 256 + to * 8) = pk.u;
    }
  }
}

// ---------------------------------------------------------------------------
// Stage 2: per-edge decode from fp16 UV. 16 lanes per edge; lane l owns
// elements o = 8l..8l+7. One 16B U-load + one 16B V-load per lane.
//   out[e] = sum_o w2[o] * lrelu(U[row][o] + V[col][o] + b1[o]) + b2
// ---------------------------------------------------------------------------
__global__ __launch_bounds__(256) void edge_decode_f16_kernel(
    const int* __restrict__ eidx, const __half* __restrict__ UV,
    const float* __restrict__ b1, const float* __restrict__ W2,
    const float* __restrict__ b2, float* __restrict__ out) {
  const int lane = threadIdx.x & 15;
  const int qw = (blockIdx.x * 256 + threadIdx.x) >> 4;
  const int nqw = (gridDim.x * 256) >> 4;

  // loop-invariant fragments: lane owns o = 8*lane .. 8*lane+7
  const float4 b1a = ((const float4*)b1)[2 * lane];
  const float4 b1b = ((const float4*)b1)[2 * lane + 1];
  const float4 w2a = ((const float4*)W2)[2 * lane];
  const float4 w2b = ((const float4*)W2)[2 * lane + 1];
  const float bb[8] = {b1a.x, b1a.y, b1a.z, b1a.w, b1b.x, b1b.y, b1b.z, b1b.w};
  const float ww[8] = {w2a.x, w2a.y, w2a.z, w2a.w, w2b.x, w2b.y, w2b.z, w2b.w};
  const float bias2 = b2[0];

  const int* __restrict__ rows = eidx;
  const int* __restrict__ cols = eidx + NE;

#pragma unroll 2
  for (int e = qw; e < NE; e += nqw) {
    const int r = rows[e];
    const int c = cols[e];
    union { uint4 u; __half2 h[4]; } Uu, Vv;
    Uu.u = *(const uint4*)(UV + (size_t)r * 256 + lane * 8);
    Vv.u = *(const uint4*)(UV + (size_t)c * 256 + 128 + lane * 8);

    float s = 0.f;
#pragma unroll
    for (int k = 0; k < 4; ++k) {
      const float2 uf = __half22float2(Uu.h[k]);
      const float2 vf = __half22float2(Vv.h[k]);
      float t0 = uf.x + vf.x + bb[2 * k];
      t0 = (t0 >= 0.f) ? t0 : 0.01f * t0;
      s = fmaf(t0, ww[2 * k], s);
      float t1 = uf.y + vf.y + bb[2 * k + 1];
      t1 = (t1 >= 0.f) ? t1 : 0.01f * t1;
      s = fmaf(t1, ww[2 * k + 1], s);
    }

    // reduce across the 16-lane group (xor masks <= 8 stay in-group)
    s += __shfl_xor(s, 8);
    s += __shfl_xor(s, 4);
    s += __shfl_xor(s, 2);
    s += __shfl_xor(s, 1);
    if (lane == 0) out[e] = s + bias2;
  }
}

// ---------------------------------------------------------------------------
// Fallback (only if workspace is too small): direct per-edge fp32 compute.
// ---------------------------------------------------------------------------
__global__ __launch_bounds__(64) void edge_direct_kernel(
    const float* __restrict__ z, const int* __restrict__ eidx,
    const float* __restrict__ W1, const float* __restrict__ b1,
    const float* __restrict__ W2, const float* __restrict__ b2,
    float* __restrict__ out) {
  const int lane = threadIdx.x;
  const int o0 = lane, o1 = lane + 64;
  const float w2_0 = W2[o0], w2_1 = W2[o1];
  const float b1_0 = b1[o0], b1_1 = b1[o1];
  const float bias2 = b2[0];

  for (int e = blockIdx.x; e < NE; e += gridDim.x) {
    const int r = eidx[e];
    const int c = eidx[e + NE];
    const float* __restrict__ zr = z + (size_t)r * HC;
    const float* __restrict__ zc = z + (size_t)c * HC;
    float a0 = 0.f, a1 = 0.f;
    for (int h = 0; h < HC; ++h) {
      const float zrh = zr[h], zch = zc[h];
      a0 = fmaf(zrh, W1[(size_t)o0 * 256 + h], a0);
      a0 = fmaf(zch, W1[(size_t)o0 * 256 + 128 + h], a0);
      a1 = fmaf(zrh, W1[(size_t)o1 * 256 + h], a1);
      a1 = fmaf(zch, W1[(size_t)o1 * 256 + 128 + h], a1);
    }
    a0 += b1_0; a1 += b1_1;
    a0 = (a0 >= 0.f) ? a0 : 0.01f * a0;
    a1 = (a1 >= 0.f) ? a1 : 0.01f * a1;
    float s = fmaf(a0, w2_0, a1 * w2_1);
    for (int off = 32; off >= 1; off >>= 1) s += __shfl_xor(s, off);
    if (lane == 0) out[e] = s + bias2;
  }
}

extern "C" void kernel_launch(void* const* d_in, const int* in_sizes, int n_in,
                              void* d_out, int out_size, void* d_ws, size_t ws_size,
                              hipStream_t stream) {
  const float* z  = (const float*)d_in[0];
  const int*   ei = (const int*)d_in[1];
  const float* W1 = (const float*)d_in[2];
  const float* b1 = (const float*)d_in[3];
  const float* W2 = (const float*)d_in[4];
  const float* b2 = (const float*)d_in[5];
  float* out = (float*)d_out;

  const size_t uv_bytes = (size_t)NN * 256 * sizeof(__half);   // 51,200,000
  const size_t wt_bytes = (size_t)128 * 256 * sizeof(float);   // 131,072

  if (ws_size >= uv_bytes + wt_bytes) {
    __half* UV = (__half*)d_ws;
    float* Wt = (float*)((char*)d_ws + uv_bytes);
    transpose_w1_kernel<<<128, 256, 0, stream>>>(W1, Wt);
    precompute_uv_f16_kernel<<<(NN + 63) / 64, 256, 0, stream>>>(z, Wt, UV);
    edge_decode_f16_kernel<<<2048, 256, 0, stream>>>(ei, UV, b1, W2, b2, out);
  } else {
    edge_direct_kernel<<<8192, 64, 0, stream>>>(z, ei, W1, b1, W2, b2, out);
  }
}

// Round 5
// 189.856 us; speedup vs baseline: 2.4293x; 1.0595x over previous
//
#include <hip/hip_runtime.h>
#include <hip/hip_fp16.h>

#define NN 100000
#define HC 128
#define NE 1600000

typedef float f32x4 __attribute__((ext_vector_type(4)));
typedef short bf16x8 __attribute__((ext_vector_type(8)));

// round-to-nearest-even float -> bf16 (bit trick; inputs are tame, no NaN/Inf)
__device__ __forceinline__ unsigned short f2bf(float f) {
  union { float f; unsigned u; } c; c.f = f;
  unsigned u = c.u + (0x7FFFu + ((c.u >> 16) & 1u));
  return (unsigned short)(u >> 16);
}
__device__ __forceinline__ float bf2f(unsigned short b) {
  union { unsigned u; float f; } c; c.u = ((unsigned)b) << 16;
  return c.f;
}

// ---------------------------------------------------------------------------
// Prep: split W into bf16 hi/lo, laid out [o][k] (o in [0,256), k in [0,128)):
//   o <  128 : src = W1[o][k]          (U weights)
//   o >= 128 : src = W1[o-128][128+k]  (V weights)
// W1 is row-major [128][256] so src = W1[(o&127)*256 + ((o>>7)<<7) + k].
// ---------------------------------------------------------------------------
__global__ __launch_bounds__(256) void wprep_kernel(
    const float* __restrict__ W1, unsigned short* __restrict__ Wh,
    unsigned short* __restrict__ Wl) {
  const int idx = blockIdx.x * 256 + threadIdx.x;  // over 256*128
  if (idx >= 256 * 128) return;
  const int o = idx >> 7;
  const int k = idx & 127;
  const float f = W1[(size_t)(o & 127) * 256 + ((o >> 7) << 7) + k];
  const unsigned short hi = f2bf(f);
  Wh[idx] = hi;
  Wl[idx] = f2bf(f - bf2f(hi));
}

// ---------------------------------------------------------------------------
// Stage 1 (MFMA bf16x3): UV[n][o] = sum_k z[n][k]*W[o][k], fp32-accurate via
// split-bf16 (Ah*Bh + Al*Bh + Ah*Bl), stored fp16.
// Block = 4 waves; wave handles 32 nodes x all 256 outputs.
// mfma_f32_16x16x32_bf16 fragment mapping (learn_hip m89/m91 verified):
//   A-frag: lane l holds A[m = l&15][k = (l>>4)*8 + e]
//   B-frag: lane l holds B[n = l&15][k = (l>>4)*8 + e]   (B^T layout = W[o][k])
//   D:      lane l, reg r -> row m = (l>>4)*4 + r, col n = l&15
// ---------------------------------------------------------------------------
__global__ __launch_bounds__(256) void precompute_uv_mfma_kernel(
    const float* __restrict__ z, const unsigned short* __restrict__ Wh,
    const unsigned short* __restrict__ Wl, __half* __restrict__ UV) {
  const int lane = threadIdx.x & 63;
  const int wv = threadIdx.x >> 6;              // wave 0..3
  const int nb = blockIdx.x * 128 + wv * 32;    // wave's node base
  const int lr = lane & 15;
  const int lg = lane >> 4;

  // ---- load z fragments for 2 m-subtiles x 4 k-groups, split hi/lo ----
  bf16x8 ah[2][4], al[2][4];
#pragma unroll
  for (int ms = 0; ms < 2; ++ms) {
    const int node = nb + ms * 16 + lr;
    const bool ok = (node < NN);
    const float* __restrict__ zp = z + (size_t)node * HC + lg * 8;
#pragma unroll
    for (int kg = 0; kg < 4; ++kg) {
      float v[8];
      if (ok) {
        const float4 p0 = *(const float4*)(zp + kg * 32);
        const float4 p1 = *(const float4*)(zp + kg * 32 + 4);
        v[0] = p0.x; v[1] = p0.y; v[2] = p0.z; v[3] = p0.w;
        v[4] = p1.x; v[5] = p1.y; v[6] = p1.z; v[7] = p1.w;
      } else {
#pragma unroll
        for (int e = 0; e < 8; ++e) v[e] = 0.f;
      }
#pragma unroll
      for (int e = 0; e < 8; ++e) {
        const unsigned short hi = f2bf(v[e]);
        ah[ms][kg][e] = (short)hi;
        al[ms][kg][e] = (short)f2bf(v[e] - bf2f(hi));
      }
    }
  }

  // ---- loop over 16 output tiles of 16 ----
#pragma unroll 1
  for (int nt = 0; nt < 16; ++nt) {
    const unsigned short* __restrict__ wph = Wh + (nt * 16 + lr) * 128 + lg * 8;
    const unsigned short* __restrict__ wpl = Wl + (nt * 16 + lr) * 128 + lg * 8;

    f32x4 acc0 = {0.f, 0.f, 0.f, 0.f};
    f32x4 acc1 = {0.f, 0.f, 0.f, 0.f};
#pragma unroll
    for (int kg = 0; kg < 4; ++kg) {
      const bf16x8 bh = *(const bf16x8*)(wph + kg * 32);
      const bf16x8 bl = *(const bf16x8*)(wpl + kg * 32);
      acc0 = __builtin_amdgcn_mfma_f32_16x16x32_bf16(ah[0][kg], bh, acc0, 0, 0, 0);
      acc0 = __builtin_amdgcn_mfma_f32_16x16x32_bf16(al[0][kg], bh, acc0, 0, 0, 0);
      acc0 = __builtin_amdgcn_mfma_f32_16x16x32_bf16(ah[0][kg], bl, acc0, 0, 0, 0);
      acc1 = __builtin_amdgcn_mfma_f32_16x16x32_bf16(ah[1][kg], bh, acc1, 0, 0, 0);
      acc1 = __builtin_amdgcn_mfma_f32_16x16x32_bf16(al[1][kg], bh, acc1, 0, 0, 0);
      acc1 = __builtin_amdgcn_mfma_f32_16x16x32_bf16(ah[1][kg], bl, acc1, 0, 0, 0);
    }

    // ---- store: D row = lg*4 + r, col = lr ----
    const int o = nt * 16 + lr;
#pragma unroll
    for (int r = 0; r < 4; ++r) {
      const int n0 = nb + lg * 4 + r;
      if (n0 < NN) UV[(size_t)n0 * 256 + o] = __float2half(acc0[r]);
      const int n1 = nb + 16 + lg * 4 + r;
      if (n1 < NN) UV[(size_t)n1 * 256 + o] = __float2half(acc1[r]);
    }
  }
}

// ---------------------------------------------------------------------------
// Stage 2: per-edge decode from fp16 UV (unchanged from round 4).
// 16 lanes per edge; lane l owns o = 8l..8l+7.
// ---------------------------------------------------------------------------
__global__ __launch_bounds__(256) void edge_decode_f16_kernel(
    const int* __restrict__ eidx, const __half* __restrict__ UV,
    const float* __restrict__ b1, const float* __restrict__ W2,
    const float* __restrict__ b2, float* __restrict__ out) {
  const int lane = threadIdx.x & 15;
  const int qw = (blockIdx.x * 256 + threadIdx.x) >> 4;
  const int nqw = (gridDim.x * 256) >> 4;

  const float4 b1a = ((const float4*)b1)[2 * lane];
  const float4 b1b = ((const float4*)b1)[2 * lane + 1];
  const float4 w2a = ((const float4*)W2)[2 * lane];
  const float4 w2b = ((const float4*)W2)[2 * lane + 1];
  const float bb[8] = {b1a.x, b1a.y, b1a.z, b1a.w, b1b.x, b1b.y, b1b.z, b1b.w};
  const float ww[8] = {w2a.x, w2a.y, w2a.z, w2a.w, w2b.x, w2b.y, w2b.z, w2b.w};
  const float bias2 = b2[0];

  const int* __restrict__ rows = eidx;
  const int* __restrict__ cols = eidx + NE;

#pragma unroll 2
  for (int e = qw; e < NE; e += nqw) {
    const int r = rows[e];
    const int c = cols[e];
    union { uint4 u; __half2 h[4]; } Uu, Vv;
    Uu.u = *(const uint4*)(UV + (size_t)r * 256 + lane * 8);
    Vv.u = *(const uint4*)(UV + (size_t)c * 256 + 128 + lane * 8);

    float s = 0.f;
#pragma unroll
    for (int k = 0; k < 4; ++k) {
      const float2 uf = __half22float2(Uu.h[k]);
      const float2 vf = __half22float2(Vv.h[k]);
      float t0 = uf.x + vf.x + bb[2 * k];
      t0 = (t0 >= 0.f) ? t0 : 0.01f * t0;
      s = fmaf(t0, ww[2 * k], s);
      float t1 = uf.y + vf.y + bb[2 * k + 1];
      t1 = (t1 >= 0.f) ? t1 : 0.01f * t1;
      s = fmaf(t1, ww[2 * k + 1], s);
    }

    s += __shfl_xor(s, 8);
    s += __shfl_xor(s, 4);
    s += __shfl_xor(s, 2);
    s += __shfl_xor(s, 1);
    if (lane == 0) out[e] = s + bias2;
  }
}

// ---------------------------------------------------------------------------
// Fallback (only if workspace is too small): direct per-edge fp32 compute.
// ---------------------------------------------------------------------------
__global__ __launch_bounds__(64) void edge_direct_kernel(
    const float* __restrict__ z, const int* __restrict__ eidx,
    const float* __restrict__ W1, const float* __restrict__ b1,
    const float* __restrict__ W2, const float* __restrict__ b2,
    float* __restrict__ out) {
  const int lane = threadIdx.x;
  const int o0 = lane, o1 = lane + 64;
  const float w2_0 = W2[o0], w2_1 = W2[o1];
  const float b1_0 = b1[o0], b1_1 = b1[o1];
  const float bias2 = b2[0];

  for (int e = blockIdx.x; e < NE; e += gridDim.x) {
    const int r = eidx[e];
    const int c = eidx[e + NE];
    const float* __restrict__ zr = z + (size_t)r * HC;
    const float* __restrict__ zc = z + (size_t)c * HC;
    float a0 = 0.f, a1 = 0.f;
    for (int h = 0; h < HC; ++h) {
      const float zrh = zr[h], zch = zc[h];
      a0 = fmaf(zrh, W1[(size_t)o0 * 256 + h], a0);
      a0 = fmaf(zch, W1[(size_t)o0 * 256 + 128 + h], a0);
      a1 = fmaf(zrh, W1[(size_t)o1 * 256 + h], a1);
      a1 = fmaf(zch, W1[(size_t)o1 * 256 + 128 + h], a1);
    }
    a0 += b1_0; a1 += b1_1;
    a0 = (a0 >= 0.f) ? a0 : 0.01f * a0;
    a1 = (a1 >= 0.f) ? a1 : 0.01f * a1;
    float s = fmaf(a0, w2_0, a1 * w2_1);
    for (int off = 32; off >= 1; off >>= 1) s += __shfl_xor(s, off);
    if (lane == 0) out[e] = s + bias2;
  }
}

extern "C" void kernel_launch(void* const* d_in, const int* in_sizes, int n_in,
                              void* d_out, int out_size, void* d_ws, size_t ws_size,
                              hipStream_t stream) {
  const float* z  = (const float*)d_in[0];
  const int*   ei = (const int*)d_in[1];
  const float* W1 = (const float*)d_in[2];
  const float* b1 = (const float*)d_in[3];
  const float* W2 = (const float*)d_in[4];
  const float* b2 = (const float*)d_in[5];
  float* out = (float*)d_out;

  const size_t uv_bytes = (size_t)NN * 256 * sizeof(__half);        // 51,200,000
  const size_t w_bytes  = (size_t)256 * 128 * sizeof(unsigned short); // 65,536 each

  if (ws_size >= uv_bytes + 2 * w_bytes) {
    __half* UV = (__half*)d_ws;
    unsigned short* Wh = (unsigned short*)((char*)d_ws + uv_bytes);
    unsigned short* Wl = Wh + 256 * 128;
    wprep_kernel<<<128, 256, 0, stream>>>(W1, Wh, Wl);
    precompute_uv_mfma_kernel<<<(NN + 127) / 128, 256, 0, stream>>>(z, Wh, Wl, UV);
    edge_decode_f16_kernel<<<2048, 256, 0, stream>>>(ei, UV, b1, W2, b2, out);
  } else {
    edge_direct_kernel<<<8192, 64, 0, stream>>>(z, ei, W1, b1, W2, b2, out);
  }
}

// Round 7
// 187.244 us; speedup vs baseline: 2.4632x; 1.0140x over previous
//
#include <hip/hip_runtime.h>
#include <hip/hip_fp16.h>

#define NN 100000
#define HC 128
#define NE 1600000

typedef float f32x4 __attribute__((ext_vector_type(4)));
typedef short bf16x8 __attribute__((ext_vector_type(8)));

// round-to-nearest-even float -> bf16 (bit trick; inputs are tame, no NaN/Inf)
__device__ __forceinline__ unsigned short f2bf(float f) {
  union { float f; unsigned u; } c; c.f = f;
  unsigned u = c.u + (0x7FFFu + ((c.u >> 16) & 1u));
  return (unsigned short)(u >> 16);
}
__device__ __forceinline__ float bf2f(unsigned short b) {
  union { unsigned u; float f; } c; c.u = ((unsigned)b) << 16;
  return c.f;
}

// ---------------------------------------------------------------------------
// Prep: split W into bf16 hi/lo, laid out [o][k] (o in [0,256), k in [0,128)):
//   o <  128 : src = W1[o][k]          (U weights)
//   o >= 128 : src = W1[o-128][128+k]  (V weights)
// ---------------------------------------------------------------------------
__global__ __launch_bounds__(256) void wprep_kernel(
    const float* __restrict__ W1, unsigned short* __restrict__ Wh,
    unsigned short* __restrict__ Wl) {
  const int idx = blockIdx.x * 256 + threadIdx.x;  // over 256*128
  if (idx >= 256 * 128) return;
  const int o = idx >> 7;
  const int k = idx & 127;
  const float f = W1[(size_t)(o & 127) * 256 + ((o >> 7) << 7) + k];
  const unsigned short hi = f2bf(f);
  Wh[idx] = hi;
  Wl[idx] = f2bf(f - bf2f(hi));
}

// ---------------------------------------------------------------------------
// Stage 1 (MFMA bf16x3, SWAPPED roles): D[m=o][n=node] so each lane ends up
// holding 4 CONSECUTIVE outputs for one node -> packed 8-byte fp16 stores.
//   A-frag = W  : lane l holds W[o = nt*16 + (l&15)][k = (l>>4)*8 + e]
//   B-frag = z  : lane l holds z[node = base + (l&15)][k = (l>>4)*8 + e]
//   D:  lane l, reg r -> o = nt*16 + (l>>4)*4 + r, node = base + (l&15)
// Wave = 32 nodes x 256 outputs; block = 4 waves = 128 nodes.
// fp32 accuracy via split-bf16 (Ah*Bh + Al*Bh + Ah*Bl), fp16 store.
// ---------------------------------------------------------------------------
__global__ __launch_bounds__(256) void precompute_uv_mfma2_kernel(
    const float* __restrict__ z, const unsigned short* __restrict__ Wh,
    const unsigned short* __restrict__ Wl, __half* __restrict__ UV) {
  const int lane = threadIdx.x & 63;
  const int wv = threadIdx.x >> 6;              // wave 0..3
  const int nb = blockIdx.x * 128 + wv * 32;    // wave's node base
  const int lr = lane & 15;
  const int lg = lane >> 4;

  // ---- load z fragments (B): 2 node-subtiles x 4 k-groups, split hi/lo ----
  bf16x8 bh[2][4], bl[2][4];
#pragma unroll
  for (int ms = 0; ms < 2; ++ms) {
    const int node = nb + ms * 16 + lr;
    const bool ok = (node < NN);
    const float* __restrict__ zp = z + (size_t)node * HC + lg * 8;
#pragma unroll
    for (int kg = 0; kg < 4; ++kg) {
      float v[8];
      if (ok) {
        const float4 p0 = *(const float4*)(zp + kg * 32);
        const float4 p1 = *(const float4*)(zp + kg * 32 + 4);
        v[0] = p0.x; v[1] = p0.y; v[2] = p0.z; v[3] = p0.w;
        v[4] = p1.x; v[5] = p1.y; v[6] = p1.z; v[7] = p1.w;
      } else {
#pragma unroll
        for (int e = 0; e < 8; ++e) v[e] = 0.f;
      }
#pragma unroll
      for (int e = 0; e < 8; ++e) {
        const unsigned short hi = f2bf(v[e]);
        bh[ms][kg][e] = (short)hi;
        bl[ms][kg][e] = (short)f2bf(v[e] - bf2f(hi));
      }
    }
  }

  // ---- loop over 16 output tiles of 16 ----
#pragma unroll 1
  for (int nt = 0; nt < 16; ++nt) {
    const unsigned short* __restrict__ wph = Wh + (nt * 16 + lr) * 128 + lg * 8;
    const unsigned short* __restrict__ wpl = Wl + (nt * 16 + lr) * 128 + lg * 8;

    f32x4 acc0 = {0.f, 0.f, 0.f, 0.f};   // node-subtile 0
    f32x4 acc1 = {0.f, 0.f, 0.f, 0.f};   // node-subtile 1
#pragma unroll
    for (int kg = 0; kg < 4; ++kg) {
      const bf16x8 ah = *(const bf16x8*)(wph + kg * 32);
      const bf16x8 al = *(const bf16x8*)(wpl + kg * 32);
      acc0 = __builtin_amdgcn_mfma_f32_16x16x32_bf16(ah, bh[0][kg], acc0, 0, 0, 0);
      acc0 = __builtin_amdgcn_mfma_f32_16x16x32_bf16(al, bh[0][kg], acc0, 0, 0, 0);
      acc0 = __builtin_amdgcn_mfma_f32_16x16x32_bf16(ah, bl[0][kg], acc0, 0, 0, 0);
      acc1 = __builtin_amdgcn_mfma_f32_16x16x32_bf16(ah, bh[1][kg], acc1, 0, 0, 0);
      acc1 = __builtin_amdgcn_mfma_f32_16x16x32_bf16(al, bh[1][kg], acc1, 0, 0, 0);
      acc1 = __builtin_amdgcn_mfma_f32_16x16x32_bf16(ah, bl[1][kg], acc1, 0, 0, 0);
    }

    // ---- packed store: lane holds o = nt*16 + lg*4 + (0..3) for its node ----
    const int ob = nt * 16 + lg * 4;
    {
      const int node = nb + lr;
      if (node < NN) {
        union { uint2 u; __half2 h[2]; } pk;
        pk.h[0] = __floats2half2_rn(acc0[0], acc0[1]);
        pk.h[1] = __floats2half2_rn(acc0[2], acc0[3]);
        *(uint2*)(UV + (size_t)node * 256 + ob) = pk.u;
      }
      const int node1 = nb + 16 + lr;
      if (node1 < NN) {
        union { uint2 u; __half2 h[2]; } pk;
        pk.h[0] = __floats2half2_rn(acc1[0], acc1[1]);
        pk.h[1] = __floats2half2_rn(acc1[2], acc1[3]);
        *(uint2*)(UV + (size_t)node1 * 256 + ob) = pk.u;
      }
    }
  }
}

// ---------------------------------------------------------------------------
// Stage 2: per-edge decode from fp16 UV (unchanged). 16 lanes per edge;
// lane l owns o = 8l..8l+7.
// ---------------------------------------------------------------------------
__global__ __launch_bounds__(256) void edge_decode_f16_kernel(
    const int* __restrict__ eidx, const __half* __restrict__ UV,
    const float* __restrict__ b1, const float* __restrict__ W2,
    const float* __restrict__ b2, float* __restrict__ out) {
  const int lane = threadIdx.x & 15;
  const int qw = (blockIdx.x * 256 + threadIdx.x) >> 4;
  const int nqw = (gridDim.x * 256) >> 4;

  const float4 b1a = ((const float4*)b1)[2 * lane];
  const float4 b1b = ((const float4*)b1)[2 * lane + 1];
  const float4 w2a = ((const float4*)W2)[2 * lane];
  const float4 w2b = ((const float4*)W2)[2 * lane + 1];
  const float bb[8] = {b1a.x, b1a.y, b1a.z, b1a.w, b1b.x, b1b.y, b1b.z, b1b.w};
  const float ww[8] = {w2a.x, w2a.y, w2a.z, w2a.w, w2b.x, w2b.y, w2b.z, w2b.w};
  const float bias2 = b2[0];

  const int* __restrict__ rows = eidx;
  const int* __restrict__ cols = eidx + NE;

#pragma unroll 2
  for (int e = qw; e < NE; e += nqw) {
    const int r = rows[e];
    const int c = cols[e];
    union { uint4 u; __half2 h[4]; } Uu, Vv;
    Uu.u = *(const uint4*)(UV + (size_t)r * 256 + lane * 8);
    Vv.u = *(const uint4*)(UV + (size_t)c * 256 + 128 + lane * 8);

    float s = 0.f;
#pragma unroll
    for (int k = 0; k < 4; ++k) {
      const float2 uf = __half22float2(Uu.h[k]);
      const float2 vf = __half22float2(Vv.h[k]);
      float t0 = uf.x + vf.x + bb[2 * k];
      t0 = (t0 >= 0.f) ? t0 : 0.01f * t0;
      s = fmaf(t0, ww[2 * k], s);
      float t1 = uf.y + vf.y + bb[2 * k + 1];
      t1 = (t1 >= 0.f) ? t1 : 0.01f * t1;
      s = fmaf(t1, ww[2 * k + 1], s);
    }

    s += __shfl_xor(s, 8);
    s += __shfl_xor(s, 4);
    s += __shfl_xor(s, 2);
    s += __shfl_xor(s, 1);
    if (lane == 0) out[e] = s + bias2;
  }
}

// ---------------------------------------------------------------------------
// Fallback (only if workspace is too small): direct per-edge fp32 compute.
// ---------------------------------------------------------------------------
__global__ __launch_bounds__(64) void edge_direct_kernel(
    const float* __restrict__ z, const int* __restrict__ eidx,
    const float* __restrict__ W1, const float* __restrict__ b1,
    const float* __restrict__ W2, const float* __restrict__ b2,
    float* __restrict__ out) {
  const int lane = threadIdx.x;
  const int o0 = lane, o1 = lane + 64;
  const float w2_0 = W2[o0], w2_1 = W2[o1];
  const float b1_0 = b1[o0], b1_1 = b1[o1];
  const float bias2 = b2[0];

  for (int e = blockIdx.x; e < NE; e += gridDim.x) {
    const int r = eidx[e];
    const int c = eidx[e + NE];
    const float* __restrict__ zr = z + (size_t)r * HC;
    const float* __restrict__ zc = z + (size_t)c * HC;
    float a0 = 0.f, a1 = 0.f;
    for (int h = 0; h < HC; ++h) {
      const float zrh = zr[h], zch = zc[h];
      a0 = fmaf(zrh, W1[(size_t)o0 * 256 + h], a0);
      a0 = fmaf(zch, W1[(size_t)o0 * 256 + 128 + h], a0);
      a1 = fmaf(zrh, W1[(size_t)o1 * 256 + h], a1);
      a1 = fmaf(zch, W1[(size_t)o1 * 256 + 128 + h], a1);
    }
    a0 += b1_0; a1 += b1_1;
    a0 = (a0 >= 0.f) ? a0 : 0.01f * a0;
    a1 = (a1 >= 0.f) ? a1 : 0.01f * a1;
    float s = fmaf(a0, w2_0, a1 * w2_1);
    for (int off = 32; off >= 1; off >>= 1) s += __shfl_xor(s, off);
    if (lane == 0) out[e] = s + bias2;
  }
}

extern "C" void kernel_launch(void* const* d_in, const int* in_sizes, int n_in,
                              void* d_out, int out_size, void* d_ws, size_t ws_size,
                              hipStream_t stream) {
  const float* z  = (const float*)d_in[0];
  const int*   ei = (const int*)d_in[1];
  const float* W1 = (const float*)d_in[2];
  const float* b1 = (const float*)d_in[3];
  const float* W2 = (const float*)d_in[4];
  const float* b2 = (const float*)d_in[5];
  float* out = (float*)d_out;

  const size_t uv_bytes = (size_t)NN * 256 * sizeof(__half);          // 51,200,000
  const size_t w_bytes  = (size_t)256 * 128 * sizeof(unsigned short); // 65,536 each

  if (ws_size >= uv_bytes + 2 * w_bytes) {
    __half* UV = (__half*)d_ws;
    unsigned short* Wh = (unsigned short*)((char*)d_ws + uv_bytes);
    unsigned short* Wl = Wh + 256 * 128;
    wprep_kernel<<<128, 256, 0, stream>>>(W1, Wh, Wl);
    precompute_uv_mfma2_kernel<<<(NN + 127) / 128, 256, 0, stream>>>(z, Wh, Wl, UV);
    edge_decode_f16_kernel<<<2048, 256, 0, stream>>>(ei, UV, b1, W2, b2, out);
  } else {
    edge_direct_kernel<<<8192, 64, 0, stream>>>(z, ei, W1, b1, W2, b2, out);
  }
}